// Round 1
// baseline (124.827 us; speedup 1.0000x reference)
//
#include <hip/hip_runtime.h>

#define F_N 100000
#define V_N 30000
#define DD 15          // domain size D
#define TILE 225       // D*D

// ---- workspace layout (in floats) ----
// belief : [0, V_N*DD)              = 450000 floats
// accum  : [V_N*DD, V_N*DD+3)      {per_f_sum, cost_sum, ent_sum}
// dist   : [DIST_OFF, +V_N*DD)
// amax   : int[V_N] at AMAX_OFF
static const int BELIEF_OFF = 0;
static const int ACCUM_OFF  = V_N * DD;            // 450000
static const int DIST_OFF   = V_N * DD + 16;       // 450016 (aligned)
static const int AMAX_OFF   = DIST_OFF + V_N * DD; // 900016

__global__ void k_init(float* __restrict__ ws) {
    int i = blockIdx.x * blockDim.x + threadIdx.x;
    if (i < V_N * DD + 3) ws[i] = 0.0f;   // zero belief + accumulators
}

// One thread per (factor, r) with r in [0,30): r<15 -> row-min i=r (m_f2rv),
// r>=15 -> col-min j=r-15 (m_f2cv). Branch-free predicated addressing.
__global__ void k_minplus_scatter(const float* __restrict__ msgs,
                                  const float* __restrict__ cost,
                                  const int*   __restrict__ scat,
                                  float* __restrict__ belief) {
    int tid = blockIdx.x * blockDim.x + threadIdx.x;
    if (tid >= F_N * 30) return;
    int f = tid / 30;
    int r = tid - f * 30;
    bool is_row = (r < DD);
    int i = is_row ? r : (r - DD);
    const float* Cf = cost + (size_t)f * TILE;
    // row-min uses m_cv2f = msgs[F_N + f]; col-min uses m_rv2f = msgs[f]
    const float* mb = msgs + (size_t)(is_row ? (F_N + f) : f) * DD;
    float mn = 1e30f;
#pragma unroll
    for (int k = 0; k < DD; ++k) {
        int a = is_row ? (i * DD + k) : (k * DD + i);
        mn = fminf(mn, Cf[a] + mb[k]);
    }
    // m_f2rv row f -> scatter index scat[f]; m_f2cv row f -> scat[F_N + f]
    int v = scat[is_row ? f : (F_N + f)];
    atomicAdd(&belief[v * DD + i], mn);
}

// One thread per variable: dist = softmax(-belief), entropy, row-argmax.
__global__ void k_softmax_ent(const float* __restrict__ belief,
                              float* __restrict__ dist,
                              int*   __restrict__ amax,
                              float* __restrict__ accum) {
    int v = blockIdx.x * blockDim.x + threadIdx.x;
    float entp = 0.0f;
    if (v < V_N) {
        float b[DD];
        float mn = 1e30f;
#pragma unroll
        for (int k = 0; k < DD; ++k) { b[k] = belief[v * DD + k]; mn = fminf(mn, b[k]); }
        float e[DD];
        float den = 0.0f;
#pragma unroll
        for (int k = 0; k < DD; ++k) { e[k] = expf(mn - b[k]); den += e[k]; }
        float inv = 1.0f / den;
        float best = -1.0f;
        int am = 0;
#pragma unroll
        for (int k = 0; k < DD; ++k) {
            float dk = e[k] * inv;
            dist[v * DD + k] = dk;
            entp -= dk * log2f(dk + 1e-6f);
            if (dk > best) { best = dk; am = k; }   // first-max semantics
        }
        amax[v] = am;
    }
    // wave-level reduce of entropy, one atomic per wave
#pragma unroll
    for (int off = 32; off > 0; off >>= 1) entp += __shfl_down(entp, off, 64);
    if ((threadIdx.x & 63) == 0) atomicAdd(&accum[2], entp);
}

// Wave-per-factor: per_f = drv^T C dcv  (coalesced 225-float read),
// cost = C[argmax(drv), argmax(dcv)]. Hierarchical reduction.
__global__ void k_factor_loss(const float* __restrict__ cost,
                              const float* __restrict__ dist,
                              const int*   __restrict__ amax,
                              const int*   __restrict__ rv_idx,
                              const int*   __restrict__ cv_idx,
                              float* __restrict__ accum) {
    int gtid = blockIdx.x * blockDim.x + threadIdx.x;
    int wid  = gtid >> 6;
    int lane = threadIdx.x & 63;
    int nw   = (gridDim.x * blockDim.x) >> 6;
    float accP = 0.0f, accC = 0.0f;
    for (int f = wid; f < F_N; f += nw) {
        int rv = rv_idx[f], cv = cv_idx[f];
        const float* dr = dist + (size_t)rv * DD;
        const float* dc = dist + (size_t)cv * DD;
        const float* Cf = cost + (size_t)f * TILE;
        float s = 0.0f;
#pragma unroll
        for (int t = 0; t < 4; ++t) {
            int e = lane + t * 64;
            if (e < TILE) {
                int i = e / DD;
                int j = e - i * DD;
                s += dr[i] * Cf[e] * dc[j];
            }
        }
#pragma unroll
        for (int off = 32; off > 0; off >>= 1) s += __shfl_down(s, off, 64);
        if (lane == 0) {
            accP += s;
            accC += Cf[amax[rv] * DD + amax[cv]];
        }
    }
    __shared__ float sP[4], sC[4];
    int w = threadIdx.x >> 6;
    if (lane == 0) { sP[w] = accP; sC[w] = accC; }
    __syncthreads();
    if (threadIdx.x == 0) {
        float tp = 0.0f, tc = 0.0f;
        int nwb = blockDim.x >> 6;
        for (int q = 0; q < nwb; ++q) { tp += sP[q]; tc += sC[q]; }
        atomicAdd(&accum[0], tp);
        atomicAdd(&accum[1], tc);
    }
}

__global__ void k_final(const float* __restrict__ accum, float* __restrict__ out) {
    if (threadIdx.x == 0 && blockIdx.x == 0) {
        // loss = sum(per_f) + 0.1 * mean-entropy ; cost_mean = sum(cost)
        out[0] = accum[0] + 0.1f * (accum[2] / (float)V_N);
        out[1] = accum[1];
    }
}

extern "C" void kernel_launch(void* const* d_in, const int* in_sizes, int n_in,
                              void* d_out, int out_size, void* d_ws, size_t ws_size,
                              hipStream_t stream) {
    const float* msgs = (const float*)d_in[0];   // (4*F_N, 15)
    const float* cost = (const float*)d_in[1];   // (F_N, 15, 15)
    const int* scat   = (const int*)d_in[46];    // f2v_per_v_scatter_idxes (2*F_N)
    const int* rv     = (const int*)d_in[48];    // rv_idxes (F_N)
    const int* cv     = (const int*)d_in[49];    // cv_idxes (F_N)

    float* ws     = (float*)d_ws;
    float* belief = ws + BELIEF_OFF;
    float* accum  = ws + ACCUM_OFF;
    float* dist   = ws + DIST_OFF;
    int*   amax   = (int*)(ws + AMAX_OFF);
    float* out    = (float*)d_out;

    {
        int n = V_N * DD + 3;
        k_init<<<(n + 255) / 256, 256, 0, stream>>>(ws);
    }
    {
        int n = F_N * 30;
        k_minplus_scatter<<<(n + 255) / 256, 256, 0, stream>>>(msgs, cost, scat, belief);
    }
    {
        int n = V_N;
        k_softmax_ent<<<(n + 255) / 256, 256, 0, stream>>>(belief, dist, amax, accum);
    }
    k_factor_loss<<<1024, 256, 0, stream>>>(cost, dist, amax, rv, cv, accum);
    k_final<<<1, 64, 0, stream>>>(accum, out);
}

// Round 2
// 93.099 us; speedup vs baseline: 1.3408x; 1.3408x over previous
//
#include <hip/hip_runtime.h>

#define F_N 100000
#define V_N 30000
#define DD 15          // domain size D
#define TILE 225       // D*D
#define NSLOT 256      // spread-accumulator slots
#define MPB 8          // factors per block in minplus kernel

// ---- workspace layout (in floats) ----
static const int BELIEF_OFF = 0;                    // 450000 floats
static const int SLOTP_OFF  = 450048;               // 256 (per_f partials)
static const int SLOTC_OFF  = 450304;               // 256 (cost partials)
static const int ENT_OFF    = 450560;               // 1   (entropy sum)
static const int DIST_OFF   = 450576;               // 450000
static const int AMAX_OFF   = 900576;               // 30000 ints
static const int ZERO_N     = 450576;               // zero [0, DIST_OFF)

__global__ void k_init(float* __restrict__ ws) {
    int i = blockIdx.x * blockDim.x + threadIdx.x;
    if (i < ZERO_N) ws[i] = 0.0f;
}

// Block handles MPB=8 factors. Stage 8x225 cost floats + 16 msg rows in LDS
// (coalesced), then 8x30 threads compute row/col mins and scatter-add.
__global__ __launch_bounds__(256) void k_minplus_scatter(
        const float* __restrict__ msgs,
        const float* __restrict__ cost,
        const int*   __restrict__ scat,
        float* __restrict__ belief) {
    __shared__ float tile[MPB * TILE];     // 1800 floats
    __shared__ float mlds[2 * MPB * DD];   // 240 floats: [0,120)=rv2f, [120,240)=cv2f
    int f0  = blockIdx.x * MPB;
    int tid = threadIdx.x;

    const float* src = cost + (size_t)f0 * TILE;
    for (int e = tid; e < MPB * TILE; e += 256) tile[e] = src[e];
    if (tid < 2 * MPB * DD) {
        mlds[tid] = (tid < MPB * DD) ? msgs[(size_t)f0 * DD + tid]
                                     : msgs[(size_t)(F_N + f0) * DD + (tid - MPB * DD)];
    }
    __syncthreads();

    int q = tid >> 5;          // factor within block (8 groups of 32)
    int r = tid & 31;          // 0..29 active
    if (r < 30) {
        bool is_row = (r < DD);
        int i = is_row ? r : (r - DD);
        int f = f0 + q;
        // row-min (m_f2rv) uses m_cv2f = msgs[F_N+f]; col-min uses m_rv2f = msgs[f]
        const float* mb = is_row ? &mlds[MPB * DD + q * DD] : &mlds[q * DD];
        const float* Cf = &tile[q * TILE];
        float mn = 1e30f;
#pragma unroll
        for (int k = 0; k < DD; ++k) {
            int a = is_row ? (i * DD + k) : (k * DD + i);
            mn = fminf(mn, Cf[a] + mb[k]);
        }
        int v = scat[is_row ? f : (F_N + f)];
        atomicAdd(&belief[v * DD + i], mn);
    }
}

// One thread per variable: dist = softmax(-belief), entropy, row-argmax.
__global__ void k_softmax_ent(const float* __restrict__ belief,
                              float* __restrict__ dist,
                              int*   __restrict__ amax,
                              float* __restrict__ ent) {
    int v = blockIdx.x * blockDim.x + threadIdx.x;
    float entp = 0.0f;
    if (v < V_N) {
        float b[DD];
        float mn = 1e30f;
#pragma unroll
        for (int k = 0; k < DD; ++k) { b[k] = belief[v * DD + k]; mn = fminf(mn, b[k]); }
        float e[DD];
        float den = 0.0f;
#pragma unroll
        for (int k = 0; k < DD; ++k) { e[k] = expf(mn - b[k]); den += e[k]; }
        float inv = 1.0f / den;
        float best = -1.0f;
        int am = 0;
#pragma unroll
        for (int k = 0; k < DD; ++k) {
            float dk = e[k] * inv;
            dist[v * DD + k] = dk;
            entp -= dk * log2f(dk + 1e-6f);
            if (dk > best) { best = dk; am = k; }   // first-max semantics
        }
        amax[v] = am;
    }
#pragma unroll
    for (int off = 32; off > 0; off >>= 1) entp += __shfl_down(entp, off, 64);
    if ((threadIdx.x & 63) == 0) atomicAdd(ent, entp);
}

// One wave per factor (no loop): per_f = drv^T C dcv, cost = C[amax,amax].
// Block-level partials spread across NSLOT slots (avoids same-address atomics).
__global__ __launch_bounds__(256) void k_factor_loss(
        const float* __restrict__ cost,
        const float* __restrict__ dist,
        const int*   __restrict__ amax,
        const int*   __restrict__ rv_idx,
        const int*   __restrict__ cv_idx,
        float* __restrict__ slotP,
        float* __restrict__ slotC) {
    int gtid = blockIdx.x * 256 + threadIdx.x;
    int f    = gtid >> 6;
    int lane = threadIdx.x & 63;
    float s = 0.0f, c = 0.0f;
    if (f < F_N) {
        int rv = rv_idx[f], cv = cv_idx[f];
        const float* dr = dist + (size_t)rv * DD;
        const float* dc = dist + (size_t)cv * DD;
        const float* Cf = cost + (size_t)f * TILE;
#pragma unroll
        for (int t = 0; t < 4; ++t) {
            int e = lane + t * 64;
            if (e < TILE) {
                int i = e / DD;
                int j = e - i * DD;
                s += dr[i] * Cf[e] * dc[j];
            }
        }
        if (lane == 0) c = Cf[amax[rv] * DD + amax[cv]];
    }
#pragma unroll
    for (int off = 32; off > 0; off >>= 1) s += __shfl_down(s, off, 64);
    __shared__ float sP[4], sC[4];
    int w = threadIdx.x >> 6;
    if (lane == 0) { sP[w] = s; sC[w] = c; }
    __syncthreads();
    if (threadIdx.x == 0) {
        float tp = sP[0] + sP[1] + sP[2] + sP[3];
        float tc = sC[0] + sC[1] + sC[2] + sC[3];
        int slot = blockIdx.x & (NSLOT - 1);
        atomicAdd(&slotP[slot], tp);
        atomicAdd(&slotC[slot], tc);
    }
}

__global__ void k_final(const float* __restrict__ slotP,
                        const float* __restrict__ slotC,
                        const float* __restrict__ ent,
                        float* __restrict__ out) {
    int t = threadIdx.x;   // 256 threads
    float p = slotP[t], c = slotC[t];
#pragma unroll
    for (int off = 32; off > 0; off >>= 1) {
        p += __shfl_down(p, off, 64);
        c += __shfl_down(c, off, 64);
    }
    __shared__ float sp[4], sc[4];
    if ((t & 63) == 0) { sp[t >> 6] = p; sc[t >> 6] = c; }
    __syncthreads();
    if (t == 0) {
        float tp = sp[0] + sp[1] + sp[2] + sp[3];
        float tc = sc[0] + sc[1] + sc[2] + sc[3];
        out[0] = tp + 0.1f * (ent[0] / (float)V_N);
        out[1] = tc;
    }
}

extern "C" void kernel_launch(void* const* d_in, const int* in_sizes, int n_in,
                              void* d_out, int out_size, void* d_ws, size_t ws_size,
                              hipStream_t stream) {
    const float* msgs = (const float*)d_in[0];   // (4*F_N, 15)
    const float* cost = (const float*)d_in[1];   // (F_N, 15, 15)
    const int* scat   = (const int*)d_in[46];    // f2v_per_v_scatter_idxes (2*F_N)
    const int* rv     = (const int*)d_in[48];    // rv_idxes (F_N)
    const int* cv     = (const int*)d_in[49];    // cv_idxes (F_N)

    float* ws     = (float*)d_ws;
    float* belief = ws + BELIEF_OFF;
    float* slotP  = ws + SLOTP_OFF;
    float* slotC  = ws + SLOTC_OFF;
    float* ent    = ws + ENT_OFF;
    float* dist   = ws + DIST_OFF;
    int*   amax   = (int*)(ws + AMAX_OFF);
    float* out    = (float*)d_out;

    k_init<<<(ZERO_N + 255) / 256, 256, 0, stream>>>(ws);
    k_minplus_scatter<<<F_N / MPB, 256, 0, stream>>>(msgs, cost, scat, belief);
    k_softmax_ent<<<(V_N + 255) / 256, 256, 0, stream>>>(belief, dist, amax, ent);
    k_factor_loss<<<(F_N * 64 + 255) / 256, 256, 0, stream>>>(cost, dist, amax, rv, cv, slotP, slotC);
    k_final<<<1, 256, 0, stream>>>(slotP, slotC, ent, out);
}